// Round 15
// baseline (842.431 us; speedup 1.0000x reference)
//
#include <hip/hip_runtime.h>
#include <math.h>

#define CHUNK 4096               // elements per radix-sort chunk
#define NB2   256                // conv1 partition bins
#define BSH   12                 // bin = dst >> BSH ; 4096 nodes per bin
#define CAP   32                 // LDS stage capacity per bin (records)
#define CAPW  65                 // LDS words per bin (odd -> conflict-free)
#define FG    16                 // flush group: 16 records = 128 B
#define RND   2048               // edges per staging round (256 thr * 8)
#define RNDH  1024               // ehist2 stride (256 thr * 4)
#define EPB   16384              // edges per k_part block

typedef int      i32x4 __attribute__((ext_vector_type(4)));
typedef float    f32x4 __attribute__((ext_vector_type(4)));
typedef unsigned u32x2 __attribute__((ext_vector_type(2)));
typedef unsigned u32x4 __attribute__((ext_vector_type(4)));

__device__ __forceinline__ i32x4 ntld4i(const int* p)   { return __builtin_nontemporal_load((const i32x4*)p); }
__device__ __forceinline__ f32x4 ntld4f(const float* p) { return __builtin_nontemporal_load((const f32x4*)p); }

// fast-math transcendentals (native v_exp/v_log path); rel err ~1e-6 on m,
// vs 1.6e-2 output threshold. Branchless sigmoid: exp(-x)->inf => 0, exact.
__device__ __forceinline__ float sigmoidf_(float x) {
    return 1.0f / (1.0f + __expf(-x));
}
__device__ __forceinline__ float softplusf_(float x) {
    return fmaxf(x, 0.0f) + __logf(1.0f + __expf(-fabsf(x)));
}
__device__ __forceinline__ unsigned key_desc(float f) {
    unsigned u = __float_as_uint(f);
    unsigned ka = (u & 0x80000000u) ? ~u : (u | 0x80000000u);
    return ~ka;
}
__device__ __forceinline__ float edge_m(float xd, float xs, float a,
                                        float wf0, float wf1, float wf2, float b0,
                                        float ws0, float ws1, float ws2, float b1) {
    float f = xd * wf0 + xs * wf1 + a * wf2 + b0;
    float g = xd * ws0 + xs * ws1 + a * ws2 + b1;
    return sigmoidf_(f) * softplusf_(g);
}

// ---------------- score constants + stats/ghist zeroing ----------------
__global__ void k_consts(const float* __restrict__ pw1, const float* __restrict__ pw2,
                         const float* __restrict__ pw3, float* __restrict__ consts,
                         float* __restrict__ stats, unsigned* __restrict__ ghist,
                         int n1, int n2, int n3) {
    if (blockIdx.x == 0) {
        if (threadIdx.x < 16) stats[threadIdx.x] = 0.f;
        for (int i = threadIdx.x; i < 2048; i += 256) ghist[i] = 0u;
    }
    const float* w; int n;
    if (blockIdx.x == 0)      { w = pw1; n = n1; }
    else if (blockIdx.x == 1) { w = pw2; n = n2; }
    else                      { w = pw3; n = n3; }
    __shared__ float s1[256], s2[256];
    float a = 0.f, b = 0.f;
    for (int i = threadIdx.x; i < n; i += 256) { float v = w[i]; a += v; b += v * v; }
    s1[threadIdx.x] = a; s2[threadIdx.x] = b; __syncthreads();
    for (int o = 128; o > 0; o >>= 1) {
        if (threadIdx.x < o) { s1[threadIdx.x] += s1[threadIdx.x + o]; s2[threadIdx.x] += s2[threadIdx.x + o]; }
        __syncthreads();
    }
    if (threadIdx.x == 0) consts[blockIdx.x] = s1[0] / sqrtf(s2[0]);
}

// ============== conv1: atomic-free two-level partition ==============
__global__ void __launch_bounds__(256) k_ehist2(const int* __restrict__ dst,
                                                unsigned* __restrict__ hist,
                                                int e0, int e1) {
    __shared__ unsigned h[NB2];
    int t = threadIdx.x;
    h[t] = 0;
    __syncthreads();
    int cs = e0 + blockIdx.x * EPB;
    int ce = cs + EPB; if (ce > e1) ce = e1;
    for (int eb = cs; eb < ce; eb += RNDH) {
        int i = eb + t * 4;
        if (eb + RNDH <= ce) {
            i32x4 d4 = ntld4i(dst + i);
            atomicAdd(&h[((unsigned)d4.x) >> BSH], 1u);
            atomicAdd(&h[((unsigned)d4.y) >> BSH], 1u);
            atomicAdd(&h[((unsigned)d4.z) >> BSH], 1u);
            atomicAdd(&h[((unsigned)d4.w) >> BSH], 1u);
        } else {
            #pragma unroll
            for (int j = 0; j < 4; ++j)
                if (i + j < ce) atomicAdd(&h[((unsigned)dst[i + j]) >> BSH], 1u);
        }
    }
    __syncthreads();
    hist[(size_t)blockIdx.x * NB2 + t] = h[t];
}

// scanA: per-digit exclusive prefix over blocks; rmask rounds entries
__global__ void k_scanA(const unsigned* __restrict__ hist, unsigned* __restrict__ offs,
                        unsigned* __restrict__ tot, int G, unsigned rmask) {
    int d = blockIdx.x, ND = gridDim.x, t = threadIdx.x;
    __shared__ unsigned s[256];
    unsigned carry = 0;
    for (int tile = 0; tile * 256 < G; ++tile) {
        int g = tile * 256 + t;
        unsigned v = (g < G) ? ((hist[(size_t)g * ND + d] + rmask) & ~rmask) : 0u;
        s[t] = v; __syncthreads();
        for (int o = 1; o < 256; o <<= 1) {
            unsigned u = (t >= o) ? s[t - o] : 0u;
            __syncthreads();
            s[t] += u; __syncthreads();
        }
        if (g < G) offs[(size_t)g * ND + d] = s[t] - v + carry;
        unsigned tl = s[255]; __syncthreads();
        carry += tl;
    }
    if (t == 0) tot[d] = carry;
}

// Phase C: stage 8B records/bin in LDS; worklist-driven aligned 128B flush
// 8 edges/thread/round (2x gather MLP), ngrp-group flush keeps rem <= 15.
__global__ void __launch_bounds__(256) k_part(
        const float* __restrict__ x, const float* __restrict__ ea,
        const int* __restrict__ src, const int* __restrict__ dst,
        const float* __restrict__ Wf, const float* __restrict__ bf,
        const float* __restrict__ Ws, const float* __restrict__ bs,
        const unsigned* __restrict__ offs, const unsigned* __restrict__ tot,
        const unsigned* __restrict__ eh,
        uint2* __restrict__ rec, int e0, int e1) {
    __shared__ unsigned stage[NB2 * CAPW];
    __shared__ unsigned gcur[NB2], fil[NB2], gend[NB2];
    __shared__ unsigned short wl[2][NB2];
    __shared__ unsigned wlc[2];
    int t = threadIdx.x;
    {
        unsigned v = tot[t];
        stage[t] = v; __syncthreads();
        for (int o = 1; o < 256; o <<= 1) {
            unsigned u = (t >= o) ? stage[t - o] : 0u;
            __syncthreads();
            stage[t] += u; __syncthreads();
        }
        unsigned g0 = (stage[t] - v) + offs[(size_t)blockIdx.x * NB2 + t];
        unsigned cnt = eh[(size_t)blockIdx.x * NB2 + t];
        gcur[t] = g0;
        gend[t] = g0 + ((cnt + FG - 1) & ~(unsigned)(FG - 1));
        fil[t] = 0;
        if (t < 2) wlc[t] = 0;
    }
    __syncthreads();
    int cs = e0 + blockIdx.x * EPB;
    int ce = cs + EPB; if (ce > e1) ce = e1;
    float wf0 = Wf[0], wf1 = Wf[1], wf2 = Wf[2], b0 = bf[0];
    float ws0 = Ws[0], ws1 = Ws[1], ws2 = Ws[2], b1 = bs[0];
    int sg = t >> 4, ln = t & 15;
    int rnd = 0;
    for (int rb = cs; rb < ce; rb += RND, ++rnd) {
        int cur = rnd & 1;
        int s8[8], d8[8]; float a8[8]; int nv;
        int eb = rb + t * 8;
        if (rb + RND <= ce) {
            i32x4 sv0 = ntld4i(src + eb);
            i32x4 sv1 = ntld4i(src + eb + 4);
            i32x4 dv0 = ntld4i(dst + eb);
            i32x4 dv1 = ntld4i(dst + eb + 4);
            f32x4 av0 = ntld4f(ea + eb);
            f32x4 av1 = ntld4f(ea + eb + 4);
            s8[0]=sv0.x; s8[1]=sv0.y; s8[2]=sv0.z; s8[3]=sv0.w;
            s8[4]=sv1.x; s8[5]=sv1.y; s8[6]=sv1.z; s8[7]=sv1.w;
            d8[0]=dv0.x; d8[1]=dv0.y; d8[2]=dv0.z; d8[3]=dv0.w;
            d8[4]=dv1.x; d8[5]=dv1.y; d8[6]=dv1.z; d8[7]=dv1.w;
            a8[0]=av0.x; a8[1]=av0.y; a8[2]=av0.z; a8[3]=av0.w;
            a8[4]=av1.x; a8[5]=av1.y; a8[6]=av1.z; a8[7]=av1.w;
            nv = 8;
        } else {
            #pragma unroll
            for (int j = 0; j < 8; ++j) {
                int e = eb + j;
                bool v = e < ce;
                s8[j] = v ? src[e] : 0;
                d8[j] = v ? dst[e] : 0;
                a8[j] = v ? ea[e]  : 0.f;
            }
            nv = (eb < ce) ? (ce - eb < 8 ? ce - eb : 8) : 0;
        }
        #pragma unroll
        for (int j = 0; j < 8; ++j) {
            if (j >= nv) break;
            int d = d8[j];
            float m = edge_m(x[d], x[s8[j]], a8[j], wf0, wf1, wf2, b0, ws0, ws1, ws2, b1);
            unsigned bin = ((unsigned)d) >> BSH;
            unsigned dl  = (unsigned)(d & ((1 << BSH) - 1));
            unsigned slot = atomicAdd(&fil[bin], 1u);
            if (slot == FG - 1) {                  // crossing 16 (rem<=15 invariant)
                unsigned w = atomicAdd(&wlc[cur], 1u);
                wl[cur][w] = (unsigned short)bin;
            }
            if (slot < CAP) {
                stage[bin * CAPW + 2 * slot]     = __float_as_uint(m);
                stage[bin * CAPW + 2 * slot + 1] = dl;
            } else {
                rec[gcur[bin] + slot] = make_uint2(__float_as_uint(m), dl);  // rare
            }
        }
        __syncthreads();
        unsigned nw = wlc[cur];
        for (unsigned i = sg; i < nw; i += 16) {
            int b = wl[cur][i];
            unsigned c = fil[b], g = gcur[b];
            unsigned* st = &stage[b * CAPW];
            if (c > CAP) {           // rare drain-all (overflow already in place)
                rec[g + ln]      = make_uint2(st[2 * ln], st[2 * ln + 1]);
                rec[g + 16 + ln] = make_uint2(st[2 * (16 + ln)], st[2 * (16 + ln) + 1]);
                if (ln == 0) { gcur[b] = g + c; fil[b] = 0; }
            } else {                 // flush ngrp aligned 128B groups (1 or 2), rem <= 15
                unsigned ngrp = c >> 4;                 // c in [16,32] -> 1 or 2
                rec[g + ln] = make_uint2(st[2 * ln], st[2 * ln + 1]);
                if (ngrp == 2)
                    rec[g + 16 + ln] = make_uint2(st[2 * (16 + ln)], st[2 * (16 + ln) + 1]);
                unsigned nfl = ngrp << 4;
                unsigned rem = c - nfl;                 // <= 15
                unsigned a0 = 0, a1 = 0;
                if (ln < rem) { a0 = st[2 * (nfl + ln)]; a1 = st[2 * (nfl + ln) + 1]; }
                if (ln < rem) { st[2 * ln] = a0; st[2 * ln + 1] = a1; }
                if (ln == 0) { gcur[b] = g + nfl; fil[b] = rem; }
            }
        }
        if (t == 0) wlc[cur ^ 1] = 0;
        __syncthreads();
    }
    // tail: fil < FG guaranteed (flushed bins leave rem<=15; unflushed never hit 16)
    for (int i = 0; i < NB2 / 16; ++i) {
        int b = sg + (i << 4);
        unsigned g = gcur[b], c = fil[b], ge = gend[b];
        unsigned* st = &stage[b * CAPW];
        for (unsigned p = g + ln; p < ge; p += 16) {
            unsigned k2 = p - g;
            rec[p] = (k2 < c) ? make_uint2(st[2 * k2], st[2 * k2 + 1]) : make_uint2(0u, 0u);
        }
    }
}

// Phase D: per-bin LDS aggregation -> aggr, fused sum/sumsq stats
__global__ void __launch_bounds__(256) k_aggr2(
        const uint2* __restrict__ rec, const unsigned* __restrict__ tot,
        float* __restrict__ aggr, float* __restrict__ stats,
        int N, int accumulate, int doStats) {
    __shared__ float acc[1 << BSH];
    __shared__ unsigned sc[256];
    __shared__ unsigned sBase, sCnt;
    int t = threadIdx.x, b = blockIdx.x;
    {
        unsigned v = tot[t];
        sc[t] = v; __syncthreads();
        for (int o = 1; o < 256; o <<= 1) {
            unsigned u = (t >= o) ? sc[t - o] : 0u;
            __syncthreads();
            sc[t] += u; __syncthreads();
        }
        if (t == b) { sBase = sc[t] - v; sCnt = tot[t]; }
    }
    for (int i = t; i < (1 << BSH); i += 256) acc[i] = 0.f;
    __syncthreads();
    unsigned lo = sBase, hi = lo + sCnt;
    for (unsigned i = lo + t; i < hi; i += 256) {
        u32x2 r = __builtin_nontemporal_load((const u32x2*)&rec[i]);
        atomicAdd(&acc[r.y], __uint_as_float(r.x));
    }
    __syncthreads();
    int nb = b << BSH;
    float s = 0.f, q = 0.f;
    for (int i = t; i < (1 << BSH); i += 256) {
        int node = nb + i;
        if (node < N) {
            float v = acc[i];
            if (accumulate) v += aggr[node];
            aggr[node] = v;
            if (doStats) { s += v; q += v * v; }
        }
    }
    if (doStats) {
        __shared__ float s1[256], s2[256];
        s1[t] = s; s2[t] = q; __syncthreads();
        for (int o = 128; o > 0; o >>= 1) {
            if (t < o) { s1[t] += s1[t + o]; s2[t] += s2[t + o]; }
            __syncthreads();
        }
        if (t == 0) { atomicAdd(&stats[0], s1[0]); atomicAdd(&stats[1], s2[0]); }
    }
}

// ---------------- conv1 atomic fallback ----------------
__global__ void k_conv1(const float* __restrict__ x, const float* __restrict__ ea,
                        const int* __restrict__ src, const int* __restrict__ dst,
                        const float* __restrict__ Wf, const float* __restrict__ bf,
                        const float* __restrict__ Ws, const float* __restrict__ bs,
                        float* __restrict__ aggr, int E) {
    int e = blockIdx.x * blockDim.x + threadIdx.x;
    if (e >= E) return;
    int s = src[e], d = dst[e];
    atomicAdd(&aggr[d], edge_m(x[d], x[s], ea[e], Wf[0], Wf[1], Wf[2], bf[0],
                               Ws[0], Ws[1], Ws[2], bs[0]));
}

// ---------------- conv2: streamed vec4 src/dst, sparse atomics ----------------
__global__ void __launch_bounds__(256) k_conv2(
        const float* __restrict__ x2, const float* __restrict__ ea,
        const int* __restrict__ src, const int* __restrict__ dst,
        const int* __restrict__ nidx,
        const float* __restrict__ Wf, const float* __restrict__ bf,
        const float* __restrict__ Ws, const float* __restrict__ bs,
        float* __restrict__ aggr, int E) {
    int base = (blockIdx.x * 256 + threadIdx.x) * 4;
    if (base >= E) return;
    float wf0 = Wf[0], wf1 = Wf[1], wf2 = Wf[2], b0 = bf[0];
    float ws0 = Ws[0], ws1 = Ws[1], ws2 = Ws[2], b1 = bs[0];
    int d4[4], s4[4]; int cnt;
    if (base + 4 <= E) {
        i32x4 dv = ntld4i(dst + base);
        i32x4 sv = ntld4i(src + base);
        d4[0]=dv.x; d4[1]=dv.y; d4[2]=dv.z; d4[3]=dv.w;
        s4[0]=sv.x; s4[1]=sv.y; s4[2]=sv.z; s4[3]=sv.w;
        cnt = 4;
    } else {
        cnt = E - base;
        for (int j = 0; j < cnt; ++j) { d4[j] = dst[base + j]; s4[j] = src[base + j]; }
    }
    #pragma unroll
    for (int j = 0; j < 4; ++j) {
        if (j >= cnt) break;
        int nd = nidx[d4[j]];
        if (nd < 0) continue;
        int ns = nidx[s4[j]];
        if (ns < 0) continue;
        float a = __builtin_nontemporal_load(ea + base + j);
        atomicAdd(&aggr[nd], edge_m(x2[nd], x2[ns], a, wf0, wf1, wf2, b0, ws0, ws1, ws2, b1));
    }
}

// ---------------- sum / sumsq reduction ----------------
__global__ void k_stats(const float* __restrict__ a, int n, float* __restrict__ stats) {
    float s = 0.f, q = 0.f;
    int stride = gridDim.x * blockDim.x;
    for (int i = blockIdx.x * blockDim.x + threadIdx.x; i < n; i += stride) {
        float v = a[i]; s += v; q += v * v;
    }
    __shared__ float s1[256], s2[256];
    s1[threadIdx.x] = s; s2[threadIdx.x] = q; __syncthreads();
    for (int o = 128; o > 0; o >>= 1) {
        if (threadIdx.x < o) { s1[threadIdx.x] += s1[threadIdx.x + o]; s2[threadIdx.x] += s2[threadIdx.x + o]; }
        __syncthreads();
    }
    if (threadIdx.x == 0) { atomicAdd(&stats[0], s1[0]); atomicAdd(&stats[1], s2[0]); }
}

// ------ batchnorm + residual (+ sort-key emit, + optional nidx/aggr2 init) ------
__global__ void k_bn(const float* __restrict__ aggr, const float* __restrict__ xin,
                     const float* __restrict__ stats, const float* __restrict__ g,
                     const float* __restrict__ be, float* __restrict__ xout,
                     int n, float invn, const float* __restrict__ consts, int ci,
                     unsigned* __restrict__ keys, unsigned* __restrict__ vals,
                     int* __restrict__ nidxInit, float* __restrict__ zeroArr, int nZero) {
    int i = blockIdx.x * blockDim.x + threadIdx.x;
    if (i >= n) return;
    if (nidxInit) nidxInit[i] = -1;
    if (zeroArr && i < nZero) zeroArr[i] = 0.f;
    float mean = stats[0] * invn;
    float var  = stats[1] * invn - mean * mean;
    float inv  = 1.0f / sqrtf(var + 1e-5f);
    float v = g[0] * (aggr[i] - mean) * inv + be[0] + xin[i];
    xout[i] = v;
    float s = tanhf(v * consts[ci]);
    keys[i] = key_desc(s);
    vals[i] = (unsigned)i;
}

// ============== top-K select: ghist -> findT -> count -> compact ==============
__global__ void __launch_bounds__(256) k_ghist(const unsigned* __restrict__ keys,
                                               unsigned* __restrict__ ghist, int n) {
    __shared__ unsigned h[2048];
    int t = threadIdx.x;
    for (int i = t; i < 2048; i += 256) h[i] = 0;
    __syncthreads();
    int stride = gridDim.x * 1024;
    for (int base = blockIdx.x * 1024 + t * 4; base + 3 < n; base += stride) {
        u32x4 k4 = __builtin_nontemporal_load((const u32x4*)(keys + base));
        atomicAdd(&h[k4.x >> 21], 1u);
        atomicAdd(&h[k4.y >> 21], 1u);
        atomicAdd(&h[k4.z >> 21], 1u);
        atomicAdd(&h[k4.w >> 21], 1u);
    }
    if (blockIdx.x == 0) {
        int tail = n & ~3;
        for (int i = tail + t; i < n; i += 256)
            atomicAdd(&h[keys[i] >> 21], 1u);
    }
    __syncthreads();
    for (int i = t; i < 2048; i += 256) { unsigned v = h[i]; if (v) atomicAdd(&ghist[i], v); }
}

__global__ void k_findT(const unsigned* __restrict__ ghist, unsigned* __restrict__ sel, int K) {
    __shared__ unsigned s[256];
    int t = threadIdx.x;
    unsigned carry = 0;
    for (int tile = 0; tile < 8; ++tile) {
        unsigned v = ghist[tile * 256 + t];
        s[t] = v; __syncthreads();
        for (int o = 1; o < 256; o <<= 1) {
            unsigned u = (t >= o) ? s[t - o] : 0u;
            __syncthreads();
            s[t] += u; __syncthreads();
        }
        unsigned cum = s[t] + carry;
        if (cum >= (unsigned)K && cum - v < (unsigned)K) {
            sel[0] = (unsigned)(tile * 256 + t);
            sel[1] = cum;
        }
        unsigned tl = s[255]; __syncthreads();
        carry += tl;
    }
}

__global__ void __launch_bounds__(256) k_selcnt(const unsigned* __restrict__ keys,
                                                const unsigned* __restrict__ sel,
                                                unsigned* __restrict__ chist, int n) {
    unsigned T = sel[0];
    int t = threadIdx.x;
    int base = blockIdx.x * CHUNK;
    int end = base + CHUNK; if (end > n) end = n;
    unsigned c = 0;
    for (int i = base + t; i < end; i += 256)
        c += ((keys[i] >> 21) <= T) ? 1u : 0u;
    __shared__ unsigned s[256];
    s[t] = c; __syncthreads();
    for (int o = 128; o > 0; o >>= 1) { if (t < o) s[t] += s[t + o]; __syncthreads(); }
    if (t == 0) chist[blockIdx.x] = s[0];
}

__global__ void __launch_bounds__(256) k_selcompact(
        const unsigned* __restrict__ keys, const unsigned* __restrict__ vals,
        const unsigned* __restrict__ sel, const unsigned* __restrict__ chist,
        unsigned* __restrict__ okeys, unsigned* __restrict__ ovals, int n, int G) {
    __shared__ unsigned s[256];
    __shared__ unsigned wsum[4];
    __shared__ unsigned runS;
    unsigned T = sel[0];
    int t = threadIdx.x, wave = t >> 6, lane = t & 63;
    unsigned v = (t < G) ? chist[t] : 0u;
    s[t] = v; __syncthreads();
    for (int o = 1; o < 256; o <<= 1) {
        unsigned u = (t >= o) ? s[t - o] : 0u;
        __syncthreads();
        s[t] += u; __syncthreads();
    }
    if (t == (int)blockIdx.x) runS = s[t] - v;
    __syncthreads();
    int cbase = blockIdx.x * CHUNK;
    for (int gix = 0; gix < CHUNK / 256; ++gix) {
        int i = cbase + gix * 256 + t;
        bool selq = (i < n) && ((keys[i] >> 21) <= T);
        unsigned long long mk = __ballot(selq);
        unsigned pre = (unsigned)__popcll(mk & ((1ull << lane) - 1ull));
        if (lane == 0) wsum[wave] = (unsigned)__popcll(mk);
        __syncthreads();
        unsigned wb = runS;
        #pragma unroll
        for (int w = 0; w < 4; ++w) if (w < wave) wb += wsum[w];
        if (selq) { unsigned pos = wb + pre; okeys[pos] = keys[i]; ovals[pos] = vals[i]; }
        __syncthreads();
        if (t == 0) runS += wsum[0] + wsum[1] + wsum[2] + wsum[3];
        __syncthreads();
    }
}

// ---------------- radix sort: per-chunk histogram (vec4, runtime-count aware) ----------------
__global__ void k_hist(const unsigned* __restrict__ keys, unsigned* __restrict__ hist,
                       int n, const unsigned* __restrict__ pn, int shift) {
    if (pn) n = (int)*pn;
    __shared__ unsigned h[256];
    int t = threadIdx.x;
    h[t] = 0;
    __syncthreads();
    int base = blockIdx.x * CHUNK;
    if (base + CHUNK <= n) {
        #pragma unroll
        for (int it = 0; it < CHUNK / 1024; ++it) {
            int i = base + it * 1024 + t * 4;
            const unsigned* p = keys + i;
            unsigned k0 = p[0], k1 = p[1], k2 = p[2], k3 = p[3];
            atomicAdd(&h[(k0 >> shift) & 255u], 1u);
            atomicAdd(&h[(k1 >> shift) & 255u], 1u);
            atomicAdd(&h[(k2 >> shift) & 255u], 1u);
            atomicAdd(&h[(k3 >> shift) & 255u], 1u);
        }
    } else {
        for (int i = base + t; i < n; i += 256)
            atomicAdd(&h[(keys[i] >> shift) & 255u], 1u);
    }
    __syncthreads();
    hist[blockIdx.x * 256 + t] = h[t];
}

// ---------------- radix sort: stable scatter (4 waves; internal base scan) ----------------
__global__ void __launch_bounds__(256) k_scatter(const unsigned* __restrict__ keys,
                                                 const unsigned* __restrict__ vals,
                                                 unsigned* __restrict__ okeys,
                                                 unsigned* __restrict__ ovals,
                                                 const unsigned* __restrict__ offs,
                                                 const unsigned* __restrict__ tot,
                                                 int n, const unsigned* __restrict__ pn,
                                                 int shift) {
    if (pn) n = (int)*pn;
    if ((int)blockIdx.x * CHUNK >= n) return;
    __shared__ unsigned run[256];
    __shared__ unsigned offl[256];
    __shared__ unsigned wcnt[4][256];
    __shared__ unsigned wpre[4][256];
    __shared__ unsigned sc[256];
    int t = threadIdx.x;
    int wave = t >> 6, lane = t & 63;
    {
        unsigned v = tot[t];
        sc[t] = v; __syncthreads();
        for (int o = 1; o < 256; o <<= 1) {
            unsigned u = (t >= o) ? sc[t - o] : 0u;
            __syncthreads();
            sc[t] += u; __syncthreads();
        }
        offl[t] = offs[(size_t)blockIdx.x * 256 + t] + (sc[t] - v);
        run[t] = 0;
    }
    __syncthreads();
    int cbase = blockIdx.x * CHUNK;
    const int GROUPS = CHUNK / 256;
    for (int gix = 0; gix < GROUPS; ++gix) {
        int i = cbase + gix * 256 + t;
        bool active = i < n;
        unsigned k = active ? keys[i] : 0u;
        unsigned v = active ? vals[i] : 0u;
        unsigned d = (k >> shift) & 255u;
        unsigned long long amask = __ballot(active);
        unsigned long long bb[8];
        #pragma unroll
        for (int bit = 0; bit < 8; ++bit) bb[bit] = __ballot(active && ((d >> bit) & 1u));
        unsigned long long m = amask;
        #pragma unroll
        for (int bit = 0; bit < 8; ++bit) m &= ((d >> bit) & 1u) ? bb[bit] : ~bb[bit];
        unsigned rk = (unsigned)__popcll(m & ((1ull << lane) - 1ull));
        #pragma unroll
        for (int j = 0; j < 4; ++j) {
            unsigned dd = (unsigned)lane + j * 64u;
            unsigned long long mm = amask;
            #pragma unroll
            for (int bit = 0; bit < 8; ++bit) mm &= ((dd >> bit) & 1u) ? bb[bit] : ~bb[bit];
            wcnt[wave][dd] = (unsigned)__popcll(mm);
        }
        __syncthreads();
        {
            unsigned r = run[t];
            unsigned c0 = wcnt[0][t], c1 = wcnt[1][t], c2 = wcnt[2][t], c3 = wcnt[3][t];
            wpre[0][t] = r;
            wpre[1][t] = r + c0;
            wpre[2][t] = r + c0 + c1;
            wpre[3][t] = r + c0 + c1 + c2;
            run[t] = r + c0 + c1 + c2 + c3;
        }
        __syncthreads();
        if (active) {
            unsigned pos = offl[d] + wpre[wave][d] + rk;
            okeys[pos] = k;
            ovals[pos] = v;
        }
    }
}

// ---------------- pool gather (+ optional new_idx, + optional next-sort keys) ----------------
__global__ void k_pool(const unsigned* __restrict__ perm, const float* __restrict__ xin,
                       const float* __restrict__ consts, int ci,
                       float* __restrict__ xout, int* __restrict__ newidx, int k,
                       unsigned* __restrict__ okeys, unsigned* __restrict__ ovals, int nci) {
    int r = blockIdx.x * blockDim.x + threadIdx.x;
    if (r >= k) return;
    unsigned p = perm[r];
    float xv = xin[p];
    float s = tanhf(xv * consts[ci]);
    float o = xv * s;
    xout[r] = o;
    if (newidx) newidx[p] = r;
    if (okeys) {
        float s2 = tanhf(o * consts[nci]);
        okeys[r] = key_desc(s2);
        ovals[r] = (unsigned)r;
    }
}

// ---------------- single-block: 4-pass radix sort + pool3 + MLP + log_softmax ----------------
__global__ void __launch_bounds__(1024) k_smallsort(
        unsigned* __restrict__ kIn, unsigned* __restrict__ vIn,
        unsigned* __restrict__ kTmp, unsigned* __restrict__ vTmp,
        int n, int k3, const float* __restrict__ xin,
        const float* __restrict__ consts, int ci,
        const float* __restrict__ Wl1, const float* __restrict__ bl1,
        const float* __restrict__ Wl2, const float* __restrict__ bl2,
        float* __restrict__ out) {
    __shared__ unsigned hist[256], sc[256], run[256], offl[256];
    __shared__ unsigned wcnt[16][256];
    __shared__ unsigned wpre[16][256];
    int t = threadIdx.x;
    int wave = t >> 6, lane = t & 63;
    unsigned *ki = kIn, *vi = vIn, *ko = kTmp, *vo = vTmp;
    for (int p = 0; p < 4; ++p) {
        int shift = p * 8;
        if (t < 256) hist[t] = 0;
        __syncthreads();
        for (int i = t; i < n; i += 1024)
            atomicAdd(&hist[(ki[i] >> shift) & 255u], 1u);
        __syncthreads();
        if (t < 256) sc[t] = hist[t];
        __syncthreads();
        for (int o = 1; o < 256; o <<= 1) {
            unsigned u = 0;
            if (t < 256 && t >= o) u = sc[t - o];
            __syncthreads();
            if (t < 256) sc[t] += u;
            __syncthreads();
        }
        if (t < 256) { offl[t] = sc[t] - hist[t]; run[t] = 0; }
        __syncthreads();
        int G = (n + 1023) / 1024;
        for (int gix = 0; gix < G; ++gix) {
            int i = gix * 1024 + t;
            bool active = i < n;
            unsigned k = active ? ki[i] : 0u;
            unsigned v = active ? vi[i] : 0u;
            unsigned d = (k >> shift) & 255u;
            unsigned long long amask = __ballot(active);
            unsigned long long bb[8];
            #pragma unroll
            for (int bit = 0; bit < 8; ++bit) bb[bit] = __ballot(active && ((d >> bit) & 1u));
            unsigned long long m = amask;
            #pragma unroll
            for (int bit = 0; bit < 8; ++bit) m &= ((d >> bit) & 1u) ? bb[bit] : ~bb[bit];
            unsigned rk = (unsigned)__popcll(m & ((1ull << lane) - 1ull));
            #pragma unroll
            for (int j = 0; j < 4; ++j) {
                unsigned dd = (unsigned)lane + j * 64u;
                unsigned long long mm = amask;
                #pragma unroll
                for (int bit = 0; bit < 8; ++bit) mm &= ((dd >> bit) & 1u) ? bb[bit] : ~bb[bit];
                wcnt[wave][dd] = (unsigned)__popcll(mm);
            }
            __syncthreads();
            if (t < 256) {
                unsigned acc = run[t];
                #pragma unroll
                for (int w2 = 0; w2 < 16; ++w2) { wpre[w2][t] = acc; acc += wcnt[w2][t]; }
                run[t] = acc;
            }
            __syncthreads();
            if (active) {
                unsigned pos = offl[d] + wpre[wave][d] + rk;
                ko[pos] = k;
                vo[pos] = v;
            }
            __syncthreads();
        }
        unsigned* tp;
        tp = ki; ki = ko; ko = tp;
        tp = vi; vi = vo; vo = tp;
        __syncthreads();
    }
    float c = consts[ci];
    float b20 = bl2[0], b21 = bl2[1];
    for (int r = t; r < k3; r += 1024) {
        unsigned pidx = vIn[r];
        float xv = xin[pidx];
        float s = tanhf(xv * c);
        float o = xv * s;
        float l0 = b20, l1 = b21;
        #pragma unroll
        for (int j = 0; j < 8; ++j) {
            float h = fmaxf(o * Wl1[j] + bl1[j], 0.0f);
            l0 += h * Wl2[2 * j];
            l1 += h * Wl2[2 * j + 1];
        }
        float mx = fmaxf(l0, l1);
        float lse = mx + logf(expf(l0 - mx) + expf(l1 - mx));
        out[2 * r]     = l0 - lse;
        out[2 * r + 1] = l1 - lse;
    }
}

// ---------------- host-side radix sort driver ----------------
static void sort_pairs(hipStream_t stream, unsigned* kI, unsigned* vI,
                       unsigned* kT, unsigned* vT, unsigned* hist, unsigned* offs,
                       unsigned* tot, int n, int G, const unsigned* pn) {
    unsigned *ki = kI, *vi = vI, *ko = kT, *vo = vT;
    for (int p = 0; p < 4; ++p) {
        int shift = p * 8;
        k_hist<<<G, 256, 0, stream>>>(ki, hist, n, pn, shift);
        k_scanA<<<256, 256, 0, stream>>>(hist, offs, tot, G, 0u);
        k_scatter<<<G, 256, 0, stream>>>(ki, vi, ko, vo, offs, tot, n, pn, shift);
        unsigned* t;
        t = ki; ki = ko; ko = t;
        t = vi; vi = vo; vo = t;
    }
    // 4 passes (even): result ends in the (kI,vI) buffers
}

extern "C" void kernel_launch(void* const* d_in, const int* in_sizes, int n_in,
                              void* d_out, int out_size, void* d_ws, size_t ws_size,
                              hipStream_t stream) {
    const float* x   = (const float*)d_in[0];
    const float* ea  = (const float*)d_in[1];
    const int*   src = (const int*)d_in[2];
    const int*   dst = (const int*)d_in[3];
    const float *Wf1 = (const float*)d_in[5],  *bf1 = (const float*)d_in[6];
    const float *Ws1 = (const float*)d_in[7],  *bs1 = (const float*)d_in[8];
    const float *g1  = (const float*)d_in[9],  *be1 = (const float*)d_in[10];
    const float *Wf2 = (const float*)d_in[11], *bf2 = (const float*)d_in[12];
    const float *Ws2 = (const float*)d_in[13], *bs2 = (const float*)d_in[14];
    const float *g2  = (const float*)d_in[15], *be2 = (const float*)d_in[16];
    const float *pw1 = (const float*)d_in[17], *pw2 = (const float*)d_in[18], *pw3 = (const float*)d_in[19];
    const float *Wl1 = (const float*)d_in[20], *bl1 = (const float*)d_in[21];
    const float *Wl2 = (const float*)d_in[22], *bl2 = (const float*)d_in[23];

    const int N  = in_sizes[0];
    const int E  = in_sizes[1];
    const int K1 = 100000, K2 = 10000, K3 = 2500;

    size_t off = 0;
    auto alloc = [&](size_t bytes) { size_t o = off; off = (off + bytes + 255) & ~(size_t)255; return o; };
    char* ws = (char*)d_ws;
    size_t o_x1    = alloc((size_t)N * 4);
    size_t o_nidx  = alloc((size_t)N * 4);
    size_t o_stats = alloc(256);
    size_t o_const = alloc(256);
    size_t o_tot   = alloc(4096);
    size_t o_gh    = alloc(8192);
    size_t o_x2    = alloc((size_t)K1 * 4);
    size_t o_x3    = alloc((size_t)K1 * 4);
    size_t o_ag2   = alloc((size_t)K1 * 4);
    size_t o_x4    = alloc((size_t)K2 * 4);
    size_t o_ag1   = alloc((size_t)N * 4);
    size_t o_arena = off;

    int G1 = (N + CHUNK - 1) / CHUNK;
    size_t s_kA = 0;
    size_t s_vA = s_kA + (((size_t)N * 4 + 255) & ~(size_t)255);
    size_t s_kB = s_vA + (((size_t)N * 4 + 255) & ~(size_t)255);
    size_t s_vB = s_kB + (((size_t)N * 4 + 255) & ~(size_t)255);
    size_t s_h  = s_vB + (((size_t)N * 4 + 255) & ~(size_t)255);
    size_t s_o  = s_h  + (((size_t)G1 * 256 * 4 + 255) & ~(size_t)255);
    size_t sortSz = s_o + (size_t)G1 * 256 * 4;

    int H = 0, Eh = 0;
    size_t p_rec = 0, p_eh = 0, p_eo = 0;
    for (int h = 1; h <= 8; h <<= 1) {
        int eh_ = (E + h - 1) / h;
        eh_ = (eh_ + RND - 1) & ~(RND - 1);
        int gc_ = (eh_ + EPB - 1) / EPB;
        size_t recB = (((size_t)eh_ + (size_t)gc_ * NB2 * FG + NB2 * FG) * 8 + 255) & ~(size_t)255;
        size_t ehB  = (((size_t)gc_ * NB2 * 4) + 255) & ~(size_t)255;
        size_t eoB  = (((size_t)gc_ * NB2 * 4) + 255) & ~(size_t)255;
        size_t partSz = recB + ehB + eoB;
        size_t arenaSz = partSz > sortSz ? partSz : sortSz;
        if (o_arena + arenaSz <= ws_size && N <= (NB2 << BSH)) {
            H = h; Eh = eh_;
            p_rec = 0; p_eh = p_rec + recB; p_eo = p_eh + ehB;
            break;
        }
    }

    float*    x1     = (float*)(ws + o_x1);
    int*      nidx   = (int*)(ws + o_nidx);
    float*    stats  = (float*)(ws + o_stats);
    float*    consts = (float*)(ws + o_const);
    unsigned* tot    = (unsigned*)(ws + o_tot);
    unsigned* selp   = tot + 512;
    unsigned* ghist  = (unsigned*)(ws + o_gh);
    float*    x2     = (float*)(ws + o_x2);
    float*    x3     = (float*)(ws + o_x3);
    float*    aggr2  = (float*)(ws + o_ag2);
    float*    x4     = (float*)(ws + o_x4);
    float*    aggr1  = (float*)(ws + o_ag1);
    unsigned* kA     = (unsigned*)(ws + o_arena + s_kA);
    unsigned* vA     = (unsigned*)(ws + o_arena + s_vA);
    unsigned* kB     = (unsigned*)(ws + o_arena + s_kB);
    unsigned* vB     = (unsigned*)(ws + o_arena + s_vB);
    unsigned* hist   = (unsigned*)(ws + o_arena + s_h);
    unsigned* offs   = (unsigned*)(ws + o_arena + s_o);

    // stats + ghist zeroed in k_consts; nidx/-1 + aggr2/0 in first k_bn
    k_consts<<<3, 256, 0, stream>>>(pw1, pw2, pw3, consts, stats, ghist,
                                    in_sizes[17], in_sizes[18], in_sizes[19]);

    // ---- cgconv 1 (atomic-free partition path) ----
    if (H > 0) {
        uint2*    rec = (uint2*)(ws + o_arena + p_rec);
        unsigned* eh  = (unsigned*)(ws + o_arena + p_eh);
        unsigned* eo  = (unsigned*)(ws + o_arena + p_eo);
        int NBN = (N + (1 << BSH) - 1) >> BSH;
        for (int h = 0; h < H; ++h) {
            int e0 = h * Eh;
            int e1 = e0 + Eh; if (e1 > E) e1 = E;
            if (e0 >= e1) break;
            int GCh = (e1 - e0 + EPB - 1) / EPB;
            k_ehist2<<<GCh, 256, 0, stream>>>(dst, eh, e0, e1);
            k_scanA<<<NB2, 256, 0, stream>>>(eh, eo, tot, GCh, (unsigned)(FG - 1));
            k_part<<<GCh, 256, 0, stream>>>(x, ea, src, dst, Wf1, bf1, Ws1, bs1,
                                            eo, tot, eh, rec, e0, e1);
            k_aggr2<<<NBN, 256, 0, stream>>>(rec, tot, aggr1, stats, N,
                                             h > 0, h == H - 1 ? 1 : 0);
        }
    } else {
        hipMemsetAsync(aggr1, 0, (size_t)N * 4, stream);
        k_conv1<<<(E + 255) / 256, 256, 0, stream>>>(x, ea, src, dst, Wf1, bf1, Ws1, bs1, aggr1, E);
        k_stats<<<1024, 256, 0, stream>>>(aggr1, N, stats);
    }
    k_bn<<<(N + 255) / 256, 256, 0, stream>>>(aggr1, x, stats, g1, be1, x1, N, 1.0f / (float)N,
                                              consts, 0, kA, vA, nidx, aggr2, K1);

    // ---- pool 1 : top 100K of 1M via select + compact + small sort ----
    k_ghist<<<256, 256, 0, stream>>>(kA, ghist, N);
    k_findT<<<1, 256, 0, stream>>>(ghist, selp, K1);
    k_selcnt<<<G1, 256, 0, stream>>>(kA, selp, hist, N);
    k_selcompact<<<G1, 256, 0, stream>>>(kA, vA, selp, hist, kB, vB, N, G1);
    sort_pairs(stream, kB, vB, kA, vA, hist, offs, tot, N, G1, selp + 1);  // ends in kB/vB
    k_pool<<<(K1 + 255) / 256, 256, 0, stream>>>(vB, x1, consts, 0, x2, nidx, K1,
                                                 (unsigned*)nullptr, (unsigned*)nullptr, 0);

    // ---- cgconv 2 (filtered edges; sparse atomics) ----
    k_conv2<<<(E / 4 + 255) / 256, 256, 0, stream>>>(x2, ea, src, dst, nidx,
                                                     Wf2, bf2, Ws2, bs2, aggr2, E);
    k_stats<<<256, 256, 0, stream>>>(aggr2, K1, stats + 2);
    k_bn<<<(K1 + 255) / 256, 256, 0, stream>>>(aggr2, x2, stats + 2, g2, be2, x3, K1, 1.0f / (float)K1,
                                               consts, 1, kA, vA,
                                               (int*)nullptr, (float*)nullptr, 0);

    // ---- pool 2 : top 10K of 100K (full sort; emits pool-3 keys into kB/vB) ----
    sort_pairs(stream, kA, vA, kB, vB, hist, offs, tot, K1,
               (K1 + CHUNK - 1) / CHUNK, (const unsigned*)nullptr);   // ends in kA/vA
    k_pool<<<(K2 + 255) / 256, 256, 0, stream>>>(vA, x3, consts, 1, x4, (int*)nullptr, K2,
                                                 kB, vB, 2);

    // ---- pool 3 + sort + MLP + log_softmax : one single-block kernel ----
    k_smallsort<<<1, 1024, 0, stream>>>(kB, vB, kA, vA, K2, K3, x4, consts, 2,
                                        Wl1, bl1, Wl2, bl2, (float*)d_out);
}

// Round 16
// 831.170 us; speedup vs baseline: 1.0135x; 1.0135x over previous
//
#include <hip/hip_runtime.h>
#include <math.h>

#define CHUNK 4096               // elements per radix-sort chunk
#define NB2   256                // conv1 partition bins
#define BSH   12                 // bin = dst >> BSH ; 4096 nodes per bin
#define CAP   24                 // LDS stage capacity per bin (records)
#define CAPW  49                 // LDS words per bin (odd -> conflict-free)
#define FG    16                 // flush group: 16 records = 128 B
#define RND   1024               // edges per staging round (256 thr * 4)
#define EPB   16384              // edges per k_part block

typedef int      i32x4 __attribute__((ext_vector_type(4)));
typedef float    f32x4 __attribute__((ext_vector_type(4)));
typedef unsigned u32x2 __attribute__((ext_vector_type(2)));
typedef unsigned u32x4 __attribute__((ext_vector_type(4)));

__device__ __forceinline__ i32x4 ntld4i(const int* p)   { return __builtin_nontemporal_load((const i32x4*)p); }
__device__ __forceinline__ f32x4 ntld4f(const float* p) { return __builtin_nontemporal_load((const f32x4*)p); }

// fast-math transcendentals (native v_exp/v_log path); rel err ~1e-6 on m,
// vs 1.6e-2 output threshold. Branchless sigmoid: exp(-x)->inf => 0, exact.
__device__ __forceinline__ float sigmoidf_(float x) {
    return 1.0f / (1.0f + __expf(-x));
}
__device__ __forceinline__ float softplusf_(float x) {
    return fmaxf(x, 0.0f) + __logf(1.0f + __expf(-fabsf(x)));
}
__device__ __forceinline__ unsigned key_desc(float f) {
    unsigned u = __float_as_uint(f);
    unsigned ka = (u & 0x80000000u) ? ~u : (u | 0x80000000u);
    return ~ka;
}
__device__ __forceinline__ float edge_m(float xd, float xs, float a,
                                        float wf0, float wf1, float wf2, float b0,
                                        float ws0, float ws1, float ws2, float b1) {
    float f = xd * wf0 + xs * wf1 + a * wf2 + b0;
    float g = xd * ws0 + xs * ws1 + a * ws2 + b1;
    return sigmoidf_(f) * softplusf_(g);
}

// ---------------- score constants + stats/ghist zeroing ----------------
__global__ void k_consts(const float* __restrict__ pw1, const float* __restrict__ pw2,
                         const float* __restrict__ pw3, float* __restrict__ consts,
                         float* __restrict__ stats, unsigned* __restrict__ ghist,
                         int n1, int n2, int n3) {
    if (blockIdx.x == 0) {
        if (threadIdx.x < 16) stats[threadIdx.x] = 0.f;
        for (int i = threadIdx.x; i < 2048; i += 256) ghist[i] = 0u;
    }
    const float* w; int n;
    if (blockIdx.x == 0)      { w = pw1; n = n1; }
    else if (blockIdx.x == 1) { w = pw2; n = n2; }
    else                      { w = pw3; n = n3; }
    __shared__ float s1[256], s2[256];
    float a = 0.f, b = 0.f;
    for (int i = threadIdx.x; i < n; i += 256) { float v = w[i]; a += v; b += v * v; }
    s1[threadIdx.x] = a; s2[threadIdx.x] = b; __syncthreads();
    for (int o = 128; o > 0; o >>= 1) {
        if (threadIdx.x < o) { s1[threadIdx.x] += s1[threadIdx.x + o]; s2[threadIdx.x] += s2[threadIdx.x + o]; }
        __syncthreads();
    }
    if (threadIdx.x == 0) consts[blockIdx.x] = s1[0] / sqrtf(s2[0]);
}

// ============== conv1: atomic-free two-level partition ==============
__global__ void __launch_bounds__(256) k_ehist2(const int* __restrict__ dst,
                                                unsigned* __restrict__ hist,
                                                int e0, int e1) {
    __shared__ unsigned h[NB2];
    int t = threadIdx.x;
    h[t] = 0;
    __syncthreads();
    int cs = e0 + blockIdx.x * EPB;
    int ce = cs + EPB; if (ce > e1) ce = e1;
    for (int eb = cs; eb < ce; eb += RND) {
        int i = eb + t * 4;
        if (eb + RND <= ce) {
            i32x4 d4 = ntld4i(dst + i);
            atomicAdd(&h[((unsigned)d4.x) >> BSH], 1u);
            atomicAdd(&h[((unsigned)d4.y) >> BSH], 1u);
            atomicAdd(&h[((unsigned)d4.z) >> BSH], 1u);
            atomicAdd(&h[((unsigned)d4.w) >> BSH], 1u);
        } else {
            #pragma unroll
            for (int j = 0; j < 4; ++j)
                if (i + j < ce) atomicAdd(&h[((unsigned)dst[i + j]) >> BSH], 1u);
        }
    }
    __syncthreads();
    hist[(size_t)blockIdx.x * NB2 + t] = h[t];
}

// scanA: per-digit exclusive prefix over blocks; rmask rounds entries
__global__ void k_scanA(const unsigned* __restrict__ hist, unsigned* __restrict__ offs,
                        unsigned* __restrict__ tot, int G, unsigned rmask) {
    int d = blockIdx.x, ND = gridDim.x, t = threadIdx.x;
    __shared__ unsigned s[256];
    unsigned carry = 0;
    for (int tile = 0; tile * 256 < G; ++tile) {
        int g = tile * 256 + t;
        unsigned v = (g < G) ? ((hist[(size_t)g * ND + d] + rmask) & ~rmask) : 0u;
        s[t] = v; __syncthreads();
        for (int o = 1; o < 256; o <<= 1) {
            unsigned u = (t >= o) ? s[t - o] : 0u;
            __syncthreads();
            s[t] += u; __syncthreads();
        }
        if (g < G) offs[(size_t)g * ND + d] = s[t] - v + carry;
        unsigned tl = s[255]; __syncthreads();
        carry += tl;
    }
    if (t == 0) tot[d] = carry;
}

// Phase C: stage 8B records/bin in LDS; worklist-driven aligned 128B flush
__global__ void __launch_bounds__(256) k_part(
        const float* __restrict__ x, const float* __restrict__ ea,
        const int* __restrict__ src, const int* __restrict__ dst,
        const float* __restrict__ Wf, const float* __restrict__ bf,
        const float* __restrict__ Ws, const float* __restrict__ bs,
        const unsigned* __restrict__ offs, const unsigned* __restrict__ tot,
        const unsigned* __restrict__ eh,
        uint2* __restrict__ rec, int e0, int e1) {
    __shared__ unsigned stage[NB2 * CAPW];
    __shared__ unsigned gcur[NB2], fil[NB2], gend[NB2];
    __shared__ unsigned short wl[2][NB2];
    __shared__ unsigned wlc[2];
    int t = threadIdx.x;
    {
        unsigned v = tot[t];
        stage[t] = v; __syncthreads();
        for (int o = 1; o < 256; o <<= 1) {
            unsigned u = (t >= o) ? stage[t - o] : 0u;
            __syncthreads();
            stage[t] += u; __syncthreads();
        }
        unsigned g0 = (stage[t] - v) + offs[(size_t)blockIdx.x * NB2 + t];
        unsigned cnt = eh[(size_t)blockIdx.x * NB2 + t];
        gcur[t] = g0;
        gend[t] = g0 + ((cnt + FG - 1) & ~(unsigned)(FG - 1));
        fil[t] = 0;
        if (t < 2) wlc[t] = 0;
    }
    __syncthreads();
    int cs = e0 + blockIdx.x * EPB;
    int ce = cs + EPB; if (ce > e1) ce = e1;
    float wf0 = Wf[0], wf1 = Wf[1], wf2 = Wf[2], b0 = bf[0];
    float ws0 = Ws[0], ws1 = Ws[1], ws2 = Ws[2], b1 = bs[0];
    int sg = t >> 4, ln = t & 15;
    int rnd = 0;
    for (int rb = cs; rb < ce; rb += RND, ++rnd) {
        int cur = rnd & 1;
        int s4[4], d4[4]; float a4[4]; bool vl[4];
        int eb = rb + t * 4;
        if (rb + RND <= ce) {
            i32x4 sv = ntld4i(src + eb);
            i32x4 dv = ntld4i(dst + eb);
            f32x4 av = ntld4f(ea + eb);
            s4[0]=sv.x; s4[1]=sv.y; s4[2]=sv.z; s4[3]=sv.w;
            d4[0]=dv.x; d4[1]=dv.y; d4[2]=dv.z; d4[3]=dv.w;
            a4[0]=av.x; a4[1]=av.y; a4[2]=av.z; a4[3]=av.w;
            vl[0]=vl[1]=vl[2]=vl[3]=true;
        } else {
            #pragma unroll
            for (int j = 0; j < 4; ++j) {
                int e = eb + j;
                vl[j] = e < ce;
                s4[j] = vl[j] ? src[e] : 0;
                d4[j] = vl[j] ? dst[e] : 0;
                a4[j] = vl[j] ? ea[e]  : 0.f;
            }
        }
        #pragma unroll
        for (int j = 0; j < 4; ++j) {
            if (!vl[j]) continue;
            int d = d4[j];
            float m = edge_m(x[d], x[s4[j]], a4[j], wf0, wf1, wf2, b0, ws0, ws1, ws2, b1);
            unsigned bin = ((unsigned)d) >> BSH;
            unsigned dl  = (unsigned)(d & ((1 << BSH) - 1));
            unsigned slot = atomicAdd(&fil[bin], 1u);
            if (slot == FG - 1) {
                unsigned w = atomicAdd(&wlc[cur], 1u);
                wl[cur][w] = (unsigned short)bin;
            }
            if (slot < CAP) {
                stage[bin * CAPW + 2 * slot]     = __float_as_uint(m);
                stage[bin * CAPW + 2 * slot + 1] = dl;
            } else {
                rec[gcur[bin] + slot] = make_uint2(__float_as_uint(m), dl);  // rare
            }
        }
        __syncthreads();
        unsigned nw = wlc[cur];
        for (unsigned i = sg; i < nw; i += 16) {
            int b = wl[cur][i];
            unsigned c = fil[b], g = gcur[b];
            unsigned* st = &stage[b * CAPW];
            if (c > CAP) {
                rec[g + ln] = make_uint2(st[2 * ln], st[2 * ln + 1]);
                if (ln < CAP - 16)
                    rec[g + 16 + ln] = make_uint2(st[2 * (16 + ln)], st[2 * (16 + ln) + 1]);
                if (ln == 0) { gcur[b] = g + c; fil[b] = 0; }
            } else {
                rec[g + ln] = make_uint2(st[2 * ln], st[2 * ln + 1]);
                unsigned rem = c - FG;
                unsigned a0 = 0, a1 = 0;
                if (ln < rem) { a0 = st[2 * (FG + ln)]; a1 = st[2 * (FG + ln) + 1]; }
                if (ln < rem) { st[2 * ln] = a0; st[2 * ln + 1] = a1; }
                if (ln == 0) { gcur[b] = g + FG; fil[b] = rem; }
            }
        }
        if (t == 0) wlc[cur ^ 1] = 0;
        __syncthreads();
    }
    for (int i = 0; i < NB2 / 16; ++i) {
        int b = sg + (i << 4);
        unsigned g = gcur[b], c = fil[b], ge = gend[b];
        unsigned* st = &stage[b * CAPW];
        for (unsigned p = g + ln; p < ge; p += 16) {
            unsigned k2 = p - g;
            rec[p] = (k2 < c) ? make_uint2(st[2 * k2], st[2 * k2 + 1]) : make_uint2(0u, 0u);
        }
    }
}

// Phase D: per-bin LDS aggregation -> aggr, fused sum/sumsq stats
__global__ void __launch_bounds__(256) k_aggr2(
        const uint2* __restrict__ rec, const unsigned* __restrict__ tot,
        float* __restrict__ aggr, float* __restrict__ stats,
        int N, int accumulate, int doStats) {
    __shared__ float acc[1 << BSH];
    __shared__ unsigned sc[256];
    __shared__ unsigned sBase, sCnt;
    int t = threadIdx.x, b = blockIdx.x;
    {
        unsigned v = tot[t];
        sc[t] = v; __syncthreads();
        for (int o = 1; o < 256; o <<= 1) {
            unsigned u = (t >= o) ? sc[t - o] : 0u;
            __syncthreads();
            sc[t] += u; __syncthreads();
        }
        if (t == b) { sBase = sc[t] - v; sCnt = tot[t]; }
    }
    for (int i = t; i < (1 << BSH); i += 256) acc[i] = 0.f;
    __syncthreads();
    unsigned lo = sBase, hi = lo + sCnt;
    for (unsigned i = lo + t; i < hi; i += 256) {
        u32x2 r = __builtin_nontemporal_load((const u32x2*)&rec[i]);
        atomicAdd(&acc[r.y], __uint_as_float(r.x));
    }
    __syncthreads();
    int nb = b << BSH;
    float s = 0.f, q = 0.f;
    for (int i = t; i < (1 << BSH); i += 256) {
        int node = nb + i;
        if (node < N) {
            float v = acc[i];
            if (accumulate) v += aggr[node];
            aggr[node] = v;
            if (doStats) { s += v; q += v * v; }
        }
    }
    if (doStats) {
        __shared__ float s1[256], s2[256];
        s1[t] = s; s2[t] = q; __syncthreads();
        for (int o = 128; o > 0; o >>= 1) {
            if (t < o) { s1[t] += s1[t + o]; s2[t] += s2[t + o]; }
            __syncthreads();
        }
        if (t == 0) { atomicAdd(&stats[0], s1[0]); atomicAdd(&stats[1], s2[0]); }
    }
}

// ---------------- conv1 atomic fallback ----------------
__global__ void k_conv1(const float* __restrict__ x, const float* __restrict__ ea,
                        const int* __restrict__ src, const int* __restrict__ dst,
                        const float* __restrict__ Wf, const float* __restrict__ bf,
                        const float* __restrict__ Ws, const float* __restrict__ bs,
                        float* __restrict__ aggr, int E) {
    int e = blockIdx.x * blockDim.x + threadIdx.x;
    if (e >= E) return;
    int s = src[e], d = dst[e];
    atomicAdd(&aggr[d], edge_m(x[d], x[s], ea[e], Wf[0], Wf[1], Wf[2], bf[0],
                               Ws[0], Ws[1], Ws[2], bs[0]));
}

// ---------------- conv2: streamed vec4 src/dst, sparse atomics ----------------
__global__ void __launch_bounds__(256) k_conv2(
        const float* __restrict__ x2, const float* __restrict__ ea,
        const int* __restrict__ src, const int* __restrict__ dst,
        const int* __restrict__ nidx,
        const float* __restrict__ Wf, const float* __restrict__ bf,
        const float* __restrict__ Ws, const float* __restrict__ bs,
        float* __restrict__ aggr, int E) {
    int base = (blockIdx.x * 256 + threadIdx.x) * 4;
    if (base >= E) return;
    float wf0 = Wf[0], wf1 = Wf[1], wf2 = Wf[2], b0 = bf[0];
    float ws0 = Ws[0], ws1 = Ws[1], ws2 = Ws[2], b1 = bs[0];
    int d4[4], s4[4]; int cnt;
    if (base + 4 <= E) {
        i32x4 dv = ntld4i(dst + base);
        i32x4 sv = ntld4i(src + base);
        d4[0]=dv.x; d4[1]=dv.y; d4[2]=dv.z; d4[3]=dv.w;
        s4[0]=sv.x; s4[1]=sv.y; s4[2]=sv.z; s4[3]=sv.w;
        cnt = 4;
    } else {
        cnt = E - base;
        for (int j = 0; j < cnt; ++j) { d4[j] = dst[base + j]; s4[j] = src[base + j]; }
    }
    #pragma unroll
    for (int j = 0; j < 4; ++j) {
        if (j >= cnt) break;
        int nd = nidx[d4[j]];
        if (nd < 0) continue;
        int ns = nidx[s4[j]];
        if (ns < 0) continue;
        float a = __builtin_nontemporal_load(ea + base + j);
        atomicAdd(&aggr[nd], edge_m(x2[nd], x2[ns], a, wf0, wf1, wf2, b0, ws0, ws1, ws2, b1));
    }
}

// ---------------- sum / sumsq reduction ----------------
__global__ void k_stats(const float* __restrict__ a, int n, float* __restrict__ stats) {
    float s = 0.f, q = 0.f;
    int stride = gridDim.x * blockDim.x;
    for (int i = blockIdx.x * blockDim.x + threadIdx.x; i < n; i += stride) {
        float v = a[i]; s += v; q += v * v;
    }
    __shared__ float s1[256], s2[256];
    s1[threadIdx.x] = s; s2[threadIdx.x] = q; __syncthreads();
    for (int o = 128; o > 0; o >>= 1) {
        if (threadIdx.x < o) { s1[threadIdx.x] += s1[threadIdx.x + o]; s2[threadIdx.x] += s2[threadIdx.x + o]; }
        __syncthreads();
    }
    if (threadIdx.x == 0) { atomicAdd(&stats[0], s1[0]); atomicAdd(&stats[1], s2[0]); }
}

// ------ batchnorm + residual (+ sort-key emit, + optional nidx/aggr2 init) ------
__global__ void k_bn(const float* __restrict__ aggr, const float* __restrict__ xin,
                     const float* __restrict__ stats, const float* __restrict__ g,
                     const float* __restrict__ be, float* __restrict__ xout,
                     int n, float invn, const float* __restrict__ consts, int ci,
                     unsigned* __restrict__ keys, unsigned* __restrict__ vals,
                     int* __restrict__ nidxInit, float* __restrict__ zeroArr, int nZero) {
    int i = blockIdx.x * blockDim.x + threadIdx.x;
    if (i >= n) return;
    if (nidxInit) nidxInit[i] = -1;
    if (zeroArr && i < nZero) zeroArr[i] = 0.f;
    float mean = stats[0] * invn;
    float var  = stats[1] * invn - mean * mean;
    float inv  = 1.0f / sqrtf(var + 1e-5f);
    float v = g[0] * (aggr[i] - mean) * inv + be[0] + xin[i];
    xout[i] = v;
    float s = tanhf(v * consts[ci]);
    keys[i] = key_desc(s);
    vals[i] = (unsigned)i;
}

// ============== top-K select: ghist -> findT -> count -> compact ==============
__global__ void __launch_bounds__(256) k_ghist(const unsigned* __restrict__ keys,
                                               unsigned* __restrict__ ghist, int n) {
    __shared__ unsigned h[2048];
    int t = threadIdx.x;
    for (int i = t; i < 2048; i += 256) h[i] = 0;
    __syncthreads();
    int stride = gridDim.x * 1024;
    for (int base = blockIdx.x * 1024 + t * 4; base + 3 < n; base += stride) {
        u32x4 k4 = __builtin_nontemporal_load((const u32x4*)(keys + base));
        atomicAdd(&h[k4.x >> 21], 1u);
        atomicAdd(&h[k4.y >> 21], 1u);
        atomicAdd(&h[k4.z >> 21], 1u);
        atomicAdd(&h[k4.w >> 21], 1u);
    }
    if (blockIdx.x == 0) {
        int tail = n & ~3;
        for (int i = tail + t; i < n; i += 256)
            atomicAdd(&h[keys[i] >> 21], 1u);
    }
    __syncthreads();
    for (int i = t; i < 2048; i += 256) { unsigned v = h[i]; if (v) atomicAdd(&ghist[i], v); }
}

__global__ void k_findT(const unsigned* __restrict__ ghist, unsigned* __restrict__ sel, int K) {
    __shared__ unsigned s[256];
    int t = threadIdx.x;
    unsigned carry = 0;
    for (int tile = 0; tile < 8; ++tile) {
        unsigned v = ghist[tile * 256 + t];
        s[t] = v; __syncthreads();
        for (int o = 1; o < 256; o <<= 1) {
            unsigned u = (t >= o) ? s[t - o] : 0u;
            __syncthreads();
            s[t] += u; __syncthreads();
        }
        unsigned cum = s[t] + carry;
        if (cum >= (unsigned)K && cum - v < (unsigned)K) {
            sel[0] = (unsigned)(tile * 256 + t);
            sel[1] = cum;
        }
        unsigned tl = s[255]; __syncthreads();
        carry += tl;
    }
}

__global__ void __launch_bounds__(256) k_selcnt(const unsigned* __restrict__ keys,
                                                const unsigned* __restrict__ sel,
                                                unsigned* __restrict__ chist, int n) {
    unsigned T = sel[0];
    int t = threadIdx.x;
    int base = blockIdx.x * CHUNK;
    int end = base + CHUNK; if (end > n) end = n;
    unsigned c = 0;
    for (int i = base + t; i < end; i += 256)
        c += ((keys[i] >> 21) <= T) ? 1u : 0u;
    __shared__ unsigned s[256];
    s[t] = c; __syncthreads();
    for (int o = 128; o > 0; o >>= 1) { if (t < o) s[t] += s[t + o]; __syncthreads(); }
    if (t == 0) chist[blockIdx.x] = s[0];
}

__global__ void __launch_bounds__(256) k_selcompact(
        const unsigned* __restrict__ keys, const unsigned* __restrict__ vals,
        const unsigned* __restrict__ sel, const unsigned* __restrict__ chist,
        unsigned* __restrict__ okeys, unsigned* __restrict__ ovals, int n, int G) {
    __shared__ unsigned s[256];
    __shared__ unsigned wsum[4];
    __shared__ unsigned runS;
    unsigned T = sel[0];
    int t = threadIdx.x, wave = t >> 6, lane = t & 63;
    unsigned v = (t < G) ? chist[t] : 0u;
    s[t] = v; __syncthreads();
    for (int o = 1; o < 256; o <<= 1) {
        unsigned u = (t >= o) ? s[t - o] : 0u;
        __syncthreads();
        s[t] += u; __syncthreads();
    }
    if (t == (int)blockIdx.x) runS = s[t] - v;
    __syncthreads();
    int cbase = blockIdx.x * CHUNK;
    for (int gix = 0; gix < CHUNK / 256; ++gix) {
        int i = cbase + gix * 256 + t;
        bool selq = (i < n) && ((keys[i] >> 21) <= T);
        unsigned long long mk = __ballot(selq);
        unsigned pre = (unsigned)__popcll(mk & ((1ull << lane) - 1ull));
        if (lane == 0) wsum[wave] = (unsigned)__popcll(mk);
        __syncthreads();
        unsigned wb = runS;
        #pragma unroll
        for (int w = 0; w < 4; ++w) if (w < wave) wb += wsum[w];
        if (selq) { unsigned pos = wb + pre; okeys[pos] = keys[i]; ovals[pos] = vals[i]; }
        __syncthreads();
        if (t == 0) runS += wsum[0] + wsum[1] + wsum[2] + wsum[3];
        __syncthreads();
    }
}

// ---------------- radix sort: per-chunk histogram (vec4, runtime-count aware) ----------------
__global__ void k_hist(const unsigned* __restrict__ keys, unsigned* __restrict__ hist,
                       int n, const unsigned* __restrict__ pn, int shift) {
    if (pn) n = (int)*pn;
    __shared__ unsigned h[256];
    int t = threadIdx.x;
    h[t] = 0;
    __syncthreads();
    int base = blockIdx.x * CHUNK;
    if (base + CHUNK <= n) {
        #pragma unroll
        for (int it = 0; it < CHUNK / 1024; ++it) {
            int i = base + it * 1024 + t * 4;
            const unsigned* p = keys + i;
            unsigned k0 = p[0], k1 = p[1], k2 = p[2], k3 = p[3];
            atomicAdd(&h[(k0 >> shift) & 255u], 1u);
            atomicAdd(&h[(k1 >> shift) & 255u], 1u);
            atomicAdd(&h[(k2 >> shift) & 255u], 1u);
            atomicAdd(&h[(k3 >> shift) & 255u], 1u);
        }
    } else {
        for (int i = base + t; i < n; i += 256)
            atomicAdd(&h[(keys[i] >> shift) & 255u], 1u);
    }
    __syncthreads();
    hist[blockIdx.x * 256 + t] = h[t];
}

// ---------------- radix sort: stable scatter (4 waves; internal base scan) ----------------
__global__ void __launch_bounds__(256) k_scatter(const unsigned* __restrict__ keys,
                                                 const unsigned* __restrict__ vals,
                                                 unsigned* __restrict__ okeys,
                                                 unsigned* __restrict__ ovals,
                                                 const unsigned* __restrict__ offs,
                                                 const unsigned* __restrict__ tot,
                                                 int n, const unsigned* __restrict__ pn,
                                                 int shift) {
    if (pn) n = (int)*pn;
    if ((int)blockIdx.x * CHUNK >= n) return;
    __shared__ unsigned run[256];
    __shared__ unsigned offl[256];
    __shared__ unsigned wcnt[4][256];
    __shared__ unsigned wpre[4][256];
    __shared__ unsigned sc[256];
    int t = threadIdx.x;
    int wave = t >> 6, lane = t & 63;
    {
        unsigned v = tot[t];
        sc[t] = v; __syncthreads();
        for (int o = 1; o < 256; o <<= 1) {
            unsigned u = (t >= o) ? sc[t - o] : 0u;
            __syncthreads();
            sc[t] += u; __syncthreads();
        }
        offl[t] = offs[(size_t)blockIdx.x * 256 + t] + (sc[t] - v);
        run[t] = 0;
    }
    __syncthreads();
    int cbase = blockIdx.x * CHUNK;
    const int GROUPS = CHUNK / 256;
    for (int gix = 0; gix < GROUPS; ++gix) {
        int i = cbase + gix * 256 + t;
        bool active = i < n;
        unsigned k = active ? keys[i] : 0u;
        unsigned v = active ? vals[i] : 0u;
        unsigned d = (k >> shift) & 255u;
        unsigned long long amask = __ballot(active);
        unsigned long long bb[8];
        #pragma unroll
        for (int bit = 0; bit < 8; ++bit) bb[bit] = __ballot(active && ((d >> bit) & 1u));
        unsigned long long m = amask;
        #pragma unroll
        for (int bit = 0; bit < 8; ++bit) m &= ((d >> bit) & 1u) ? bb[bit] : ~bb[bit];
        unsigned rk = (unsigned)__popcll(m & ((1ull << lane) - 1ull));
        #pragma unroll
        for (int j = 0; j < 4; ++j) {
            unsigned dd = (unsigned)lane + j * 64u;
            unsigned long long mm = amask;
            #pragma unroll
            for (int bit = 0; bit < 8; ++bit) mm &= ((dd >> bit) & 1u) ? bb[bit] : ~bb[bit];
            wcnt[wave][dd] = (unsigned)__popcll(mm);
        }
        __syncthreads();
        {
            unsigned r = run[t];
            unsigned c0 = wcnt[0][t], c1 = wcnt[1][t], c2 = wcnt[2][t], c3 = wcnt[3][t];
            wpre[0][t] = r;
            wpre[1][t] = r + c0;
            wpre[2][t] = r + c0 + c1;
            wpre[3][t] = r + c0 + c1 + c2;
            run[t] = r + c0 + c1 + c2 + c3;
        }
        __syncthreads();
        if (active) {
            unsigned pos = offl[d] + wpre[wave][d] + rk;
            okeys[pos] = k;
            ovals[pos] = v;
        }
    }
}

// ---------------- pool gather (+ optional new_idx, + optional next-sort keys) ----------------
__global__ void k_pool(const unsigned* __restrict__ perm, const float* __restrict__ xin,
                       const float* __restrict__ consts, int ci,
                       float* __restrict__ xout, int* __restrict__ newidx, int k,
                       unsigned* __restrict__ okeys, unsigned* __restrict__ ovals, int nci) {
    int r = blockIdx.x * blockDim.x + threadIdx.x;
    if (r >= k) return;
    unsigned p = perm[r];
    float xv = xin[p];
    float s = tanhf(xv * consts[ci]);
    float o = xv * s;
    xout[r] = o;
    if (newidx) newidx[p] = r;
    if (okeys) {
        float s2 = tanhf(o * consts[nci]);
        okeys[r] = key_desc(s2);
        ovals[r] = (unsigned)r;
    }
}

// ---------------- single-block: 4-pass radix sort + pool3 + MLP + log_softmax ----------------
__global__ void __launch_bounds__(1024) k_smallsort(
        unsigned* __restrict__ kIn, unsigned* __restrict__ vIn,
        unsigned* __restrict__ kTmp, unsigned* __restrict__ vTmp,
        int n, int k3, const float* __restrict__ xin,
        const float* __restrict__ consts, int ci,
        const float* __restrict__ Wl1, const float* __restrict__ bl1,
        const float* __restrict__ Wl2, const float* __restrict__ bl2,
        float* __restrict__ out) {
    __shared__ unsigned hist[256], sc[256], run[256], offl[256];
    __shared__ unsigned wcnt[16][256];
    __shared__ unsigned wpre[16][256];
    int t = threadIdx.x;
    int wave = t >> 6, lane = t & 63;
    unsigned *ki = kIn, *vi = vIn, *ko = kTmp, *vo = vTmp;
    for (int p = 0; p < 4; ++p) {
        int shift = p * 8;
        if (t < 256) hist[t] = 0;
        __syncthreads();
        for (int i = t; i < n; i += 1024)
            atomicAdd(&hist[(ki[i] >> shift) & 255u], 1u);
        __syncthreads();
        if (t < 256) sc[t] = hist[t];
        __syncthreads();
        for (int o = 1; o < 256; o <<= 1) {
            unsigned u = 0;
            if (t < 256 && t >= o) u = sc[t - o];
            __syncthreads();
            if (t < 256) sc[t] += u;
            __syncthreads();
        }
        if (t < 256) { offl[t] = sc[t] - hist[t]; run[t] = 0; }
        __syncthreads();
        int G = (n + 1023) / 1024;
        for (int gix = 0; gix < G; ++gix) {
            int i = gix * 1024 + t;
            bool active = i < n;
            unsigned k = active ? ki[i] : 0u;
            unsigned v = active ? vi[i] : 0u;
            unsigned d = (k >> shift) & 255u;
            unsigned long long amask = __ballot(active);
            unsigned long long bb[8];
            #pragma unroll
            for (int bit = 0; bit < 8; ++bit) bb[bit] = __ballot(active && ((d >> bit) & 1u));
            unsigned long long m = amask;
            #pragma unroll
            for (int bit = 0; bit < 8; ++bit) m &= ((d >> bit) & 1u) ? bb[bit] : ~bb[bit];
            unsigned rk = (unsigned)__popcll(m & ((1ull << lane) - 1ull));
            #pragma unroll
            for (int j = 0; j < 4; ++j) {
                unsigned dd = (unsigned)lane + j * 64u;
                unsigned long long mm = amask;
                #pragma unroll
                for (int bit = 0; bit < 8; ++bit) mm &= ((dd >> bit) & 1u) ? bb[bit] : ~bb[bit];
                wcnt[wave][dd] = (unsigned)__popcll(mm);
            }
            __syncthreads();
            if (t < 256) {
                unsigned acc = run[t];
                #pragma unroll
                for (int w2 = 0; w2 < 16; ++w2) { wpre[w2][t] = acc; acc += wcnt[w2][t]; }
                run[t] = acc;
            }
            __syncthreads();
            if (active) {
                unsigned pos = offl[d] + wpre[wave][d] + rk;
                ko[pos] = k;
                vo[pos] = v;
            }
            __syncthreads();
        }
        unsigned* tp;
        tp = ki; ki = ko; ko = tp;
        tp = vi; vi = vo; vo = tp;
        __syncthreads();
    }
    float c = consts[ci];
    float b20 = bl2[0], b21 = bl2[1];
    for (int r = t; r < k3; r += 1024) {
        unsigned pidx = vIn[r];
        float xv = xin[pidx];
        float s = tanhf(xv * c);
        float o = xv * s;
        float l0 = b20, l1 = b21;
        #pragma unroll
        for (int j = 0; j < 8; ++j) {
            float h = fmaxf(o * Wl1[j] + bl1[j], 0.0f);
            l0 += h * Wl2[2 * j];
            l1 += h * Wl2[2 * j + 1];
        }
        float mx = fmaxf(l0, l1);
        float lse = mx + logf(expf(l0 - mx) + expf(l1 - mx));
        out[2 * r]     = l0 - lse;
        out[2 * r + 1] = l1 - lse;
    }
}

// ---------------- host-side radix sort driver ----------------
static void sort_pairs(hipStream_t stream, unsigned* kI, unsigned* vI,
                       unsigned* kT, unsigned* vT, unsigned* hist, unsigned* offs,
                       unsigned* tot, int n, int G, const unsigned* pn) {
    unsigned *ki = kI, *vi = vI, *ko = kT, *vo = vT;
    for (int p = 0; p < 4; ++p) {
        int shift = p * 8;
        k_hist<<<G, 256, 0, stream>>>(ki, hist, n, pn, shift);
        k_scanA<<<256, 256, 0, stream>>>(hist, offs, tot, G, 0u);
        k_scatter<<<G, 256, 0, stream>>>(ki, vi, ko, vo, offs, tot, n, pn, shift);
        unsigned* t;
        t = ki; ki = ko; ko = t;
        t = vi; vi = vo; vo = t;
    }
    // 4 passes (even): result ends in the (kI,vI) buffers
}

extern "C" void kernel_launch(void* const* d_in, const int* in_sizes, int n_in,
                              void* d_out, int out_size, void* d_ws, size_t ws_size,
                              hipStream_t stream) {
    const float* x   = (const float*)d_in[0];
    const float* ea  = (const float*)d_in[1];
    const int*   src = (const int*)d_in[2];
    const int*   dst = (const int*)d_in[3];
    const float *Wf1 = (const float*)d_in[5],  *bf1 = (const float*)d_in[6];
    const float *Ws1 = (const float*)d_in[7],  *bs1 = (const float*)d_in[8];
    const float *g1  = (const float*)d_in[9],  *be1 = (const float*)d_in[10];
    const float *Wf2 = (const float*)d_in[11], *bf2 = (const float*)d_in[12];
    const float *Ws2 = (const float*)d_in[13], *bs2 = (const float*)d_in[14];
    const float *g2  = (const float*)d_in[15], *be2 = (const float*)d_in[16];
    const float *pw1 = (const float*)d_in[17], *pw2 = (const float*)d_in[18], *pw3 = (const float*)d_in[19];
    const float *Wl1 = (const float*)d_in[20], *bl1 = (const float*)d_in[21];
    const float *Wl2 = (const float*)d_in[22], *bl2 = (const float*)d_in[23];

    const int N  = in_sizes[0];
    const int E  = in_sizes[1];
    const int K1 = 100000, K2 = 10000, K3 = 2500;

    size_t off = 0;
    auto alloc = [&](size_t bytes) { size_t o = off; off = (off + bytes + 255) & ~(size_t)255; return o; };
    char* ws = (char*)d_ws;
    size_t o_x1    = alloc((size_t)N * 4);
    size_t o_nidx  = alloc((size_t)N * 4);
    size_t o_stats = alloc(256);
    size_t o_const = alloc(256);
    size_t o_tot   = alloc(4096);
    size_t o_gh    = alloc(8192);
    size_t o_x2    = alloc((size_t)K1 * 4);
    size_t o_x3    = alloc((size_t)K1 * 4);
    size_t o_ag2   = alloc((size_t)K1 * 4);
    size_t o_x4    = alloc((size_t)K2 * 4);
    size_t o_ag1   = alloc((size_t)N * 4);
    size_t o_arena = off;

    int G1 = (N + CHUNK - 1) / CHUNK;
    size_t s_kA = 0;
    size_t s_vA = s_kA + (((size_t)N * 4 + 255) & ~(size_t)255);
    size_t s_kB = s_vA + (((size_t)N * 4 + 255) & ~(size_t)255);
    size_t s_vB = s_kB + (((size_t)N * 4 + 255) & ~(size_t)255);
    size_t s_h  = s_vB + (((size_t)N * 4 + 255) & ~(size_t)255);
    size_t s_o  = s_h  + (((size_t)G1 * 256 * 4 + 255) & ~(size_t)255);
    size_t sortSz = s_o + (size_t)G1 * 256 * 4;

    int H = 0, Eh = 0;
    size_t p_rec = 0, p_eh = 0, p_eo = 0;
    for (int h = 1; h <= 8; h <<= 1) {
        int eh_ = (E + h - 1) / h;
        eh_ = (eh_ + RND - 1) & ~(RND - 1);
        int gc_ = (eh_ + EPB - 1) / EPB;
        size_t recB = (((size_t)eh_ + (size_t)gc_ * NB2 * FG + NB2 * FG) * 8 + 255) & ~(size_t)255;
        size_t ehB  = (((size_t)gc_ * NB2 * 4) + 255) & ~(size_t)255;
        size_t eoB  = (((size_t)gc_ * NB2 * 4) + 255) & ~(size_t)255;
        size_t partSz = recB + ehB + eoB;
        size_t arenaSz = partSz > sortSz ? partSz : sortSz;
        if (o_arena + arenaSz <= ws_size && N <= (NB2 << BSH)) {
            H = h; Eh = eh_;
            p_rec = 0; p_eh = p_rec + recB; p_eo = p_eh + ehB;
            break;
        }
    }

    float*    x1     = (float*)(ws + o_x1);
    int*      nidx   = (int*)(ws + o_nidx);
    float*    stats  = (float*)(ws + o_stats);
    float*    consts = (float*)(ws + o_const);
    unsigned* tot    = (unsigned*)(ws + o_tot);
    unsigned* selp   = tot + 512;
    unsigned* ghist  = (unsigned*)(ws + o_gh);
    float*    x2     = (float*)(ws + o_x2);
    float*    x3     = (float*)(ws + o_x3);
    float*    aggr2  = (float*)(ws + o_ag2);
    float*    x4     = (float*)(ws + o_x4);
    float*    aggr1  = (float*)(ws + o_ag1);
    unsigned* kA     = (unsigned*)(ws + o_arena + s_kA);
    unsigned* vA     = (unsigned*)(ws + o_arena + s_vA);
    unsigned* kB     = (unsigned*)(ws + o_arena + s_kB);
    unsigned* vB     = (unsigned*)(ws + o_arena + s_vB);
    unsigned* hist   = (unsigned*)(ws + o_arena + s_h);
    unsigned* offs   = (unsigned*)(ws + o_arena + s_o);

    // stats + ghist zeroed in k_consts; nidx/-1 + aggr2/0 in first k_bn
    k_consts<<<3, 256, 0, stream>>>(pw1, pw2, pw3, consts, stats, ghist,
                                    in_sizes[17], in_sizes[18], in_sizes[19]);

    // ---- cgconv 1 (atomic-free partition path) ----
    if (H > 0) {
        uint2*    rec = (uint2*)(ws + o_arena + p_rec);
        unsigned* eh  = (unsigned*)(ws + o_arena + p_eh);
        unsigned* eo  = (unsigned*)(ws + o_arena + p_eo);
        int NBN = (N + (1 << BSH) - 1) >> BSH;
        for (int h = 0; h < H; ++h) {
            int e0 = h * Eh;
            int e1 = e0 + Eh; if (e1 > E) e1 = E;
            if (e0 >= e1) break;
            int GCh = (e1 - e0 + EPB - 1) / EPB;
            k_ehist2<<<GCh, 256, 0, stream>>>(dst, eh, e0, e1);
            k_scanA<<<NB2, 256, 0, stream>>>(eh, eo, tot, GCh, (unsigned)(FG - 1));
            k_part<<<GCh, 256, 0, stream>>>(x, ea, src, dst, Wf1, bf1, Ws1, bs1,
                                            eo, tot, eh, rec, e0, e1);
            k_aggr2<<<NBN, 256, 0, stream>>>(rec, tot, aggr1, stats, N,
                                             h > 0, h == H - 1 ? 1 : 0);
        }
    } else {
        hipMemsetAsync(aggr1, 0, (size_t)N * 4, stream);
        k_conv1<<<(E + 255) / 256, 256, 0, stream>>>(x, ea, src, dst, Wf1, bf1, Ws1, bs1, aggr1, E);
        k_stats<<<1024, 256, 0, stream>>>(aggr1, N, stats);
    }
    k_bn<<<(N + 255) / 256, 256, 0, stream>>>(aggr1, x, stats, g1, be1, x1, N, 1.0f / (float)N,
                                              consts, 0, kA, vA, nidx, aggr2, K1);

    // ---- pool 1 : top 100K of 1M via select + compact + small sort ----
    k_ghist<<<256, 256, 0, stream>>>(kA, ghist, N);
    k_findT<<<1, 256, 0, stream>>>(ghist, selp, K1);
    k_selcnt<<<G1, 256, 0, stream>>>(kA, selp, hist, N);
    k_selcompact<<<G1, 256, 0, stream>>>(kA, vA, selp, hist, kB, vB, N, G1);
    sort_pairs(stream, kB, vB, kA, vA, hist, offs, tot, N, G1, selp + 1);  // ends in kB/vB
    k_pool<<<(K1 + 255) / 256, 256, 0, stream>>>(vB, x1, consts, 0, x2, nidx, K1,
                                                 (unsigned*)nullptr, (unsigned*)nullptr, 0);

    // ---- cgconv 2 (filtered edges; sparse atomics) ----
    k_conv2<<<(E / 4 + 255) / 256, 256, 0, stream>>>(x2, ea, src, dst, nidx,
                                                     Wf2, bf2, Ws2, bs2, aggr2, E);
    k_stats<<<256, 256, 0, stream>>>(aggr2, K1, stats + 2);
    k_bn<<<(K1 + 255) / 256, 256, 0, stream>>>(aggr2, x2, stats + 2, g2, be2, x3, K1, 1.0f / (float)K1,
                                               consts, 1, kA, vA,
                                               (int*)nullptr, (float*)nullptr, 0);

    // ---- pool 2 : top 10K of 100K (full sort; emits pool-3 keys into kB/vB) ----
    sort_pairs(stream, kA, vA, kB, vB, hist, offs, tot, K1,
               (K1 + CHUNK - 1) / CHUNK, (const unsigned*)nullptr);   // ends in kA/vA
    k_pool<<<(K2 + 255) / 256, 256, 0, stream>>>(vA, x3, consts, 1, x4, (int*)nullptr, K2,
                                                 kB, vB, 2);

    // ---- pool 3 + sort + MLP + log_softmax : one single-block kernel ----
    k_smallsort<<<1, 1024, 0, stream>>>(kB, vB, kA, vA, K2, K3, x4, consts, 2,
                                        Wl1, bl1, Wl2, bl2, (float*)d_out);
}